// Round 7
// baseline (229.259 us; speedup 1.0000x reference)
//
#include <hip/hip_runtime.h>
#include <hip/hip_bf16.h>

typedef __attribute__((ext_vector_type(8))) short short8;
typedef __attribute__((ext_vector_type(4))) short short4v;
typedef __attribute__((ext_vector_type(4))) float f32x4;

#define MFMA16(a, b, c) __builtin_amdgcn_mfma_f32_16x16x32_bf16((a), (b), (c), 0, 0, 0)

// Plain fragment layout (A-operand rows x k, or B-operand rows x k):
//   frag*512 + lane*8 + e , lane = gq*16+jl : A row=jl, k-slot=gq*8+e (plain k).
// Pi-permuted k order (for accumulator-fed B-operands, lane-local repack):
//   k-slot (ks,gq,e) <-> d = (2*ks + (e>>2))*16 + gq*4 + (e&3)
// A-side partners (K in pwkv, wo in weight conv) are pre-stored in pi order.

__device__ __forceinline__ short f2bf(float f) {
    union { __hip_bfloat16 h; short s; } u;
    u.h = __float2bfloat16(f);
    return u.s;
}

__device__ __forceinline__ unsigned pk2(float lo, float hi) {
    unsigned a = (unsigned short)f2bf(lo);
    unsigned b = (unsigned short)f2bf(hi);
    return a | (b << 16);
}

__device__ __forceinline__ short8 pack8(const f32x4 a, const f32x4 b, float s) {
    union { short8 v; unsigned w[4]; } u;
    u.w[0] = pk2(a[0] * s, a[1] * s);
    u.w[1] = pk2(a[2] * s, a[3] * s);
    u.w[2] = pk2(b[0] * s, b[1] * s);
    u.w[3] = pk2(b[2] * s, b[3] * s);
    return u.v;
}

#define C2SCALE 0.18033688011112042f  // (1/8) * log2(e), folded into Q

// ---------------- K1: merged depthwise q (by 0-15) + depthwise kv (by 16-23)
// ---------------- + weight fp32->bf16 fragment reorder (by==24) ----------------
__global__ __launch_bounds__(256) void dw_kernel(
    const float* __restrict__ x,
    const float* __restrict__ wq_dw, const float* __restrict__ qg, const float* __restrict__ qb,
    const float* __restrict__ qm, const float* __restrict__ qv,
    const float* __restrict__ wkv_dw, const float* __restrict__ kg, const float* __restrict__ kb,
    const float* __restrict__ km, const float* __restrict__ kv,
    const float* __restrict__ wq_pw, const float* __restrict__ wkv_pw, const float* __restrict__ wo,
    short* __restrict__ qd_t, short* __restrict__ kvd_t,
    short* __restrict__ wq_bf, short* __restrict__ wkv_bf, short* __restrict__ wo_bf) {
    __shared__ float xs[16][3][16][17];
    const int cg = blockIdx.x, by = blockIdx.y, b = blockIdx.z;
    const int tid = threadIdx.x;

    if (by == 24) {  // ---- weight conversion (32 blocks x 256 thr) ----
        const int base = (b * 8 + cg) * 256 + tid;
        for (int i = base; i < 65536; i += 8192) {
            int o = i >> 7, cin = i & 127;
            wq_bf[((o >> 4) * 4 + (cin >> 5)) * 512 + (((cin >> 3) & 3) * 16 + (o & 15)) * 8 + (cin & 7)] = f2bf(wq_pw[i]);
        }
        for (int i = base; i < 131072; i += 8192) {
            int o = i >> 7, cin = i & 127;
            wkv_bf[((o >> 4) * 4 + (cin >> 5)) * 512 + (((cin >> 3) & 3) * 16 + (o & 15)) * 8 + (cin & 7)] = f2bf(wkv_pw[i]);
        }
        // wo in pi-permuted per-head fragment order for the fused out-GEMM:
        // frag = (h*2 + ks3)*8 + (co>>4); pos = frag*512 + (gq*16 + (co&15))*8 + e
        // with d2 = cin&63: m2=d2>>4, ks3=m2>>1, gq=(d2>>2)&3, r=d2&3, e=(m2&1)*4+r
        for (int i = base; i < 65536; i += 8192) {
            int co = i >> 9, cin = i & 511;
            int h = cin >> 6, d2 = cin & 63;
            int m2 = d2 >> 4, gq2 = (d2 >> 2) & 3, r2 = d2 & 3;
            int frag = ((h * 2 + (m2 >> 1)) * 8 + (co >> 4));
            wo_bf[frag * 512 + (gq2 * 16 + (co & 15)) * 8 + (m2 & 1) * 4 + r2] = f2bf(wo[i]);
        }
        return;
    }

    const int y = tid >> 4, xx = tid & 15;
    const int c0 = cg * 16;

    if (by < 16) {  // ---- depthwise q, stride 1, z = by ----
        const int z = by;
        #pragma unroll 4
        for (int ch = 0; ch < 16; ++ch)
            for (int zz = 0; zz < 3; ++zz) {
                int iz = z + zz - 1;
                float val = 0.f;
                if ((unsigned)iz < 16u)
                    val = x[(((b * 128 + c0 + ch) * 16 + iz) * 16 + y) * 16 + xx];
                xs[ch][zz][y][xx] = val;
            }
        __syncthreads();
        short res[16];
        #pragma unroll
        for (int ch = 0; ch < 16; ++ch) {
            const int c = c0 + ch;
            const float* wc = wq_dw + c * 27;
            float s = 0.f;
            #pragma unroll
            for (int zz = 0; zz < 3; ++zz)
                #pragma unroll
                for (int dy = 0; dy < 3; ++dy) {
                    int iy = y + dy - 1;
                    if ((unsigned)iy < 16u) {
                        float v  = xs[ch][zz][iy][xx];
                        float vm = __shfl_up(v, 1, 16);
                        float vp = __shfl_down(v, 1, 16);
                        float w0 = wc[zz * 9 + dy * 3 + 0];
                        float w1 = wc[zz * 9 + dy * 3 + 1];
                        float w2 = wc[zz * 9 + dy * 3 + 2];
                        if (xx > 0)  s += vm * w0;
                        s += v * w1;
                        if (xx < 15) s += vp * w2;
                    }
                }
            float sc = qg[c] * rsqrtf(qv[c] + 1e-5f);
            float sh = qb[c] - qm[c] * sc;
            res[ch] = f2bf(s * sc + sh);
        }
        const int i = z * 256 + tid;
        const int ib = i >> 4;
        short* dstb = qd_t + (long)b * 524288;
        #pragma unroll
        for (int h2 = 0; h2 < 2; ++h2) {
            short8 ov;
            #pragma unroll
            for (int k = 0; k < 8; ++k) ov[k] = res[h2 * 8 + k];
            *(short8*)(dstb + (ib * 4 + (cg >> 1)) * 512 + (((cg * 2 + h2) & 3) * 16 + xx) * 8) = ov;
        }
    } else {  // ---- depthwise kv, stride 2, oz = by - 16 ----
        const int oz = by - 16;
        #pragma unroll 4
        for (int ch = 0; ch < 16; ++ch)
            for (int zz = 0; zz < 3; ++zz) {
                int iz = 2 * oz + zz - 1;
                float val = 0.f;
                if ((unsigned)iz < 16u)
                    val = x[(((b * 128 + c0 + ch) * 16 + iz) * 16 + y) * 16 + xx];
                xs[ch][zz][y][xx] = val;
            }
        __syncthreads();
        const int pos = tid & 63, cq = tid >> 6;
        const int oy = pos >> 3, ox = pos & 7;
        short4v outv;
        #pragma unroll
        for (int cc = 0; cc < 4; ++cc) {
            const int chl = cq * 4 + cc;
            const int c = c0 + chl;
            const float* wc = wkv_dw + c * 27;
            float s = 0.f;
            #pragma unroll
            for (int zz = 0; zz < 3; ++zz)
                #pragma unroll
                for (int dy = 0; dy < 3; ++dy) {
                    int iy = 2 * oy + dy - 1;
                    if ((unsigned)iy < 16u) {
                        #pragma unroll
                        for (int dx = 0; dx < 3; ++dx) {
                            int ix = 2 * ox + dx - 1;
                            if ((unsigned)ix < 16u)
                                s += xs[chl][zz][iy][ix] * wc[zz * 9 + dy * 3 + dx];
                        }
                    }
                }
            float sc = kg[c] * rsqrtf(kv[c] + 1e-5f);
            float sh = kb[c] - km[c] * sc;
            outv[cc] = f2bf(s * sc + sh);
        }
        const int j = oz * 64 + pos;
        const int jb = j >> 4;
        short* dstb = kvd_t + (long)b * 65536;
        *(short4v*)(dstb + (jb * 4 + (cg >> 1)) * 512 +
                    (((cg * 2 + (cq >> 1)) & 3) * 16 + (j & 15)) * 8 + (cq & 1) * 4) = outv;
    }
}

// ---------------- K2: pointwise kv GEMM -> K (pi-frag) + V (PV-frag) ----------------
__global__ __launch_bounds__(256) void pwkv_kernel(
    const short* __restrict__ wkv_bf, const short* __restrict__ kvd_t,
    short* __restrict__ k_t, short* __restrict__ v_t) {
    const int e = blockIdx.x, b = blockIdx.y;
    const int bj = e >> 3, bo = e & 7;
    const int tid = threadIdx.x, lane = tid & 63, wv = tid >> 6;
    const int jl = lane & 15, gq = lane >> 4;
    const int wm = wv >> 1, wn = wv & 1;
    short8 A[4][4];
    #pragma unroll
    for (int m = 0; m < 4; ++m)
        #pragma unroll
        for (int ks = 0; ks < 4; ++ks)
            A[m][ks] = *(const short8*)(wkv_bf + (((bo * 8 + wm * 4 + m) * 4 + ks) * 512) + lane * 8);
    f32x4 acc[4][4];
    #pragma unroll
    for (int m = 0; m < 4; ++m)
        #pragma unroll
        for (int n = 0; n < 4; ++n) acc[m][n] = (f32x4){0.f, 0.f, 0.f, 0.f};
    const short* Bb = kvd_t + (long)b * 65536;
    #pragma unroll
    for (int ks = 0; ks < 4; ++ks)
        #pragma unroll
        for (int n = 0; n < 4; ++n) {
            short8 Bf = *(const short8*)(Bb + (((bj * 8 + wn * 4 + n) * 4 + ks) * 512) + lane * 8);
            #pragma unroll
            for (int m = 0; m < 4; ++m) acc[m][n] = MFMA16(A[m][ks], Bf, acc[m][n]);
        }
    const int hh = bo * 2 + wm;
    if (hh < 8) {
        // K in pi order: frag = jt*2 + (m>>1); pos = lane*8 + (m&1)*4 + r
        short* kf = k_t + ((long)(b * 8 + hh)) * 32768;
        #pragma unroll
        for (int m = 0; m < 4; ++m)
            #pragma unroll
            for (int n = 0; n < 4; ++n) {
                int jt = bj * 8 + wn * 4 + n;
                short4v pk;
                #pragma unroll
                for (int r = 0; r < 4; ++r) pk[r] = f2bf(acc[m][n][r]);
                *(short4v*)(kf + (jt * 2 + (m >> 1)) * 512 + lane * 8 + (m & 1) * 4) = pk;
            }
    } else {
        short* vf = v_t + ((long)(b * 8 + hh - 8)) * 32768;
        #pragma unroll
        for (int m = 0; m < 4; ++m)
            #pragma unroll
            for (int n = 0; n < 4; ++n) {
                int frag = ((bj * 4 + wn * 2 + (n >> 1)) * 4 + m);
                #pragma unroll
                for (int r = 0; r < 4; ++r)
                    vf[frag * 512 + ((jl >> 2) * 16 + gq * 4 + r) * 8 + (n & 1) * 4 + (jl & 3)]
                        = f2bf(acc[m][n][r]);
            }
    }
}

// ---------------- K3: FUSED  Q-proj + attention + out-proj + bias ----------------
// One wave = one 16-row i-tile. Per head: Q-proj (16 MFMA) -> QK^T (pi) ->
// max-free softmax -> PV -> normalize -> out-GEMM accumulated in registers.
// No LDS, no barriers, all operand loads are coalesced 1KB fragments.
__global__ __launch_bounds__(256) void fused_kernel(
    const short* __restrict__ wq_bf, const short* __restrict__ qd_t,
    const short* __restrict__ k_t, const short* __restrict__ v_t,
    const short* __restrict__ wo_bf, const float* __restrict__ bias,
    float* __restrict__ out) {
    const int rb = blockIdx.x, b = blockIdx.y;
    const int tid = threadIdx.x, lane = tid & 63, wv = tid >> 6;
    const int jl = lane & 15, gq = lane >> 4;
    const int it = rb * 4 + wv;  // i-tile 0..255

    // qd B-fragments (K=128 -> 4 chunks), reused by all heads
    short8 qdB[4];
    {
        const short* qdb = qd_t + (long)b * 524288;
        #pragma unroll
        for (int kc = 0; kc < 4; ++kc)
            qdB[kc] = *(const short8*)(qdb + (it * 4 + kc) * 512 + lane * 8);
    }

    f32x4 outacc[8];
    #pragma unroll
    for (int o = 0; o < 8; ++o) outacc[o] = (f32x4){0.f, 0.f, 0.f, 0.f};

    #pragma unroll 1
    for (int h = 0; h < 8; ++h) {
        const short* kf = k_t + ((long)(b * 8 + h)) * 32768;
        const short* vf = v_t + ((long)(b * 8 + h)) * 32768;
        // ---- Q-proj: qa[ot] holds Q[h*64 + ot*16 + gq*4 + r][i=jl]
        f32x4 qa[4];
        #pragma unroll
        for (int ot = 0; ot < 4; ++ot) qa[ot] = (f32x4){0.f, 0.f, 0.f, 0.f};
        #pragma unroll
        for (int kc = 0; kc < 4; ++kc)
            #pragma unroll
            for (int ot = 0; ot < 4; ++ot) {
                short8 Af = *(const short8*)(wq_bf + (((h * 4 + ot) * 4 + kc) * 512) + lane * 8);
                qa[ot] = MFMA16(Af, qdB[kc], qa[ot]);
            }
        // pack Q (pi order, scale folded): QB[ks] e -> qa[2ks + (e>>2)][e&3]
        short8 QB[2];
        QB[0] = pack8(qa[0], qa[1], C2SCALE);
        QB[1] = pack8(qa[2], qa[3], C2SCALE);

        f32x4 O[4];
        #pragma unroll
        for (int m = 0; m < 4; ++m) O[m] = (f32x4){0.f, 0.f, 0.f, 0.f};
        float l = 0.f;

        #pragma unroll 2
        for (int c = 0; c < 8; ++c) {
            // QK^T (pi on both sides): S[n]: lane holds S[j=c*64+n*16+gq*4+r][i=jl]
            f32x4 S[4];
            #pragma unroll
            for (int n = 0; n < 4; ++n) S[n] = (f32x4){0.f, 0.f, 0.f, 0.f};
            #pragma unroll
            for (int n = 0; n < 4; ++n)
                #pragma unroll
                for (int ks = 0; ks < 2; ++ks) {
                    short8 Kf = *(const short8*)(kf + ((c * 4 + n) * 2 + ks) * 512 + lane * 8);
                    S[n] = MFMA16(Kf, QB[ks], S[n]);
                }
            short8 VA[2][4];
            #pragma unroll
            for (int ks2 = 0; ks2 < 2; ++ks2)
                #pragma unroll
                for (int m = 0; m < 4; ++m)
                    VA[ks2][m] = *(const short8*)(vf + ((c * 2 + ks2) * 4 + m) * 512 + lane * 8);
            // max-free softmax
            f32x4 p[4];
            #pragma unroll
            for (int n = 0; n < 4; ++n)
                #pragma unroll
                for (int r = 0; r < 4; ++r) {
                    p[n][r] = exp2f(S[n][r]);
                    l += p[n][r];
                }
            short8 PW[2];
            PW[0] = pack8(p[0], p[1], 1.f);
            PW[1] = pack8(p[2], p[3], 1.f);
            // PV
            #pragma unroll
            for (int ks2 = 0; ks2 < 2; ++ks2)
                #pragma unroll
                for (int m = 0; m < 4; ++m)
                    O[m] = MFMA16(VA[ks2][m], PW[ks2], O[m]);
        }
        // finish row-sum (rows live on jl; partials across gq lanes)
        l += __shfl_xor(l, 16, 64);
        l += __shfl_xor(l, 32, 64);
        float inv = 1.f / l;
        // pack normalized attn rows as B-frag (pi order)
        short8 PB[2];
        PB[0] = pack8(O[0], O[1], inv);
        PB[1] = pack8(O[2], O[3], inv);
        // out-GEMM: outacc[ot2] += wo_h . attn_h
        #pragma unroll
        for (int ks3 = 0; ks3 < 2; ++ks3)
            #pragma unroll
            for (int ot2 = 0; ot2 < 8; ++ot2) {
                short8 Wf = *(const short8*)(wo_bf + (((h * 2 + ks3) * 8 + ot2) * 512) + lane * 8);
                outacc[ot2] = MFMA16(Wf, PB[ks3], outacc[ot2]);
            }
    }
    // epilogue: bias + fp32 store; outacc[ot2]: lane holds out[co=ot2*16+gq*4+r][i=jl]
    const int ii = it * 16 + jl;
    #pragma unroll
    for (int ot2 = 0; ot2 < 8; ++ot2)
        #pragma unroll
        for (int r = 0; r < 4; ++r) {
            int co = ot2 * 16 + gq * 4 + r;
            out[((long)(b * 128 + co)) * 4096 + ii] = outacc[ot2][r] + bias[co];
        }
}

extern "C" void kernel_launch(void* const* d_in, const int* in_sizes, int n_in,
                              void* d_out, int out_size, void* d_ws, size_t ws_size,
                              hipStream_t stream) {
    const float* x      = (const float*)d_in[0];
    const float* wq_dw  = (const float*)d_in[1];
    const float* bnq_g  = (const float*)d_in[2];
    const float* bnq_b  = (const float*)d_in[3];
    const float* bnq_m  = (const float*)d_in[4];
    const float* bnq_v  = (const float*)d_in[5];
    const float* wq_pw  = (const float*)d_in[6];
    const float* wkv_dw = (const float*)d_in[7];
    const float* bnk_g  = (const float*)d_in[8];
    const float* bnk_b  = (const float*)d_in[9];
    const float* bnk_m  = (const float*)d_in[10];
    const float* bnk_v  = (const float*)d_in[11];
    const float* wkv_pw = (const float*)d_in[12];
    const float* w_out  = (const float*)d_in[13];
    const float* b_out  = (const float*)d_in[14];
    float* out = (float*)d_out;

    char* ws = (char*)d_ws;
    short* wq_bf  = (short*)(ws + 0);          //  512*128*2
    short* wkv_bf = (short*)(ws + 131072);     // 1024*128*2
    short* wo_bf  = (short*)(ws + 393216);     //  128*512*2
    short* qd_t   = (short*)(ws + 524288);     // 4*4096*128*2
    short* kvd_t  = (short*)(ws + 4718592);    // 4*512*128*2
    short* k_t    = (short*)(ws + 5242880);    // 4*8*512*64*2
    short* v_t    = (short*)(ws + 7340032);    // 4*8*64*512*2

    dw_kernel<<<dim3(8, 25, 4), dim3(256), 0, stream>>>(
        x, wq_dw, bnq_g, bnq_b, bnq_m, bnq_v,
        wkv_dw, bnk_g, bnk_b, bnk_m, bnk_v,
        wq_pw, wkv_pw, w_out,
        qd_t, kvd_t, wq_bf, wkv_bf, wo_bf);
    pwkv_kernel<<<dim3(32, 4), dim3(256), 0, stream>>>(wkv_bf, kvd_t, k_t, v_t);
    fused_kernel<<<dim3(64, 4), dim3(256), 0, stream>>>(wq_bf, qd_t, k_t, v_t, wo_bf, b_out, out);
}

// Round 8
// 185.868 us; speedup vs baseline: 1.2335x; 1.2335x over previous
//
#include <hip/hip_runtime.h>
#include <hip/hip_bf16.h>

typedef __attribute__((ext_vector_type(8))) short short8;
typedef __attribute__((ext_vector_type(4))) short short4v;
typedef __attribute__((ext_vector_type(4))) float f32x4;

#define MFMA16(a, b, c) __builtin_amdgcn_mfma_f32_16x16x32_bf16((a), (b), (c), 0, 0, 0)

// Plain fragment layout: frag*512 + lane*8 + e (lane = gq*16+jl).
// Pi-permuted k order (accumulator-fed B-operands, lane-local repack):
//   k-slot (ks,gq,e) <-> d = (2*ks + (e>>2))*16 + gq*4 + (e&3)
// A-side partners (K in pwkv, wo in weight conv) pre-stored in pi order.

__device__ __forceinline__ short f2bf(float f) {
    union { __hip_bfloat16 h; short s; } u;
    u.h = __float2bfloat16(f);
    return u.s;
}

__device__ __forceinline__ unsigned pk2(float lo, float hi) {
    unsigned a = (unsigned short)f2bf(lo);
    unsigned b = (unsigned short)f2bf(hi);
    return a | (b << 16);
}

__device__ __forceinline__ short8 pack8(const f32x4 a, const f32x4 b, float s) {
    union { short8 v; unsigned w[4]; } u;
    u.w[0] = pk2(a[0] * s, a[1] * s);
    u.w[1] = pk2(a[2] * s, a[3] * s);
    u.w[2] = pk2(b[0] * s, b[1] * s);
    u.w[3] = pk2(b[2] * s, b[3] * s);
    return u.v;
}

#define C2SCALE 0.18033688011112042f  // (1/8) * log2(e), folded into Q

// ---------------- K1: merged depthwise q (by 0-15) + depthwise kv (by 16-23)
// ---------------- + weight fp32->bf16 fragment reorder (by==24) ----------------
__global__ __launch_bounds__(256) void dw_kernel(
    const float* __restrict__ x,
    const float* __restrict__ wq_dw, const float* __restrict__ qg, const float* __restrict__ qb,
    const float* __restrict__ qm, const float* __restrict__ qv,
    const float* __restrict__ wkv_dw, const float* __restrict__ kg, const float* __restrict__ kb,
    const float* __restrict__ km, const float* __restrict__ kv,
    const float* __restrict__ wq_pw, const float* __restrict__ wkv_pw, const float* __restrict__ wo,
    short* __restrict__ qd_t, short* __restrict__ kvd_t,
    short* __restrict__ wq_bf, short* __restrict__ wkv_bf, short* __restrict__ wo_bf) {
    __shared__ float xs[16][3][16][17];
    const int cg = blockIdx.x, by = blockIdx.y, b = blockIdx.z;
    const int tid = threadIdx.x;

    if (by == 24) {  // ---- weight conversion (32 blocks x 256 thr) ----
        const int base = (b * 8 + cg) * 256 + tid;
        for (int i = base; i < 65536; i += 8192) {
            int o = i >> 7, cin = i & 127;
            wq_bf[((o >> 4) * 4 + (cin >> 5)) * 512 + (((cin >> 3) & 3) * 16 + (o & 15)) * 8 + (cin & 7)] = f2bf(wq_pw[i]);
        }
        for (int i = base; i < 131072; i += 8192) {
            int o = i >> 7, cin = i & 127;
            wkv_bf[((o >> 4) * 4 + (cin >> 5)) * 512 + (((cin >> 3) & 3) * 16 + (o & 15)) * 8 + (cin & 7)] = f2bf(wkv_pw[i]);
        }
        // wo in pi-permuted per-head fragment order for the fused out-GEMM
        for (int i = base; i < 65536; i += 8192) {
            int co = i >> 9, cin = i & 511;
            int h = cin >> 6, d2 = cin & 63;
            int m2 = d2 >> 4, gq2 = (d2 >> 2) & 3, r2 = d2 & 3;
            int frag = ((h * 2 + (m2 >> 1)) * 8 + (co >> 4));
            wo_bf[frag * 512 + (gq2 * 16 + (co & 15)) * 8 + (m2 & 1) * 4 + r2] = f2bf(wo[i]);
        }
        return;
    }

    const int y = tid >> 4, xx = tid & 15;
    const int c0 = cg * 16;

    if (by < 16) {  // ---- depthwise q, stride 1, z = by ----
        const int z = by;
        #pragma unroll 4
        for (int ch = 0; ch < 16; ++ch)
            for (int zz = 0; zz < 3; ++zz) {
                int iz = z + zz - 1;
                float val = 0.f;
                if ((unsigned)iz < 16u)
                    val = x[(((b * 128 + c0 + ch) * 16 + iz) * 16 + y) * 16 + xx];
                xs[ch][zz][y][xx] = val;
            }
        __syncthreads();
        short res[16];
        #pragma unroll
        for (int ch = 0; ch < 16; ++ch) {
            const int c = c0 + ch;
            const float* wc = wq_dw + c * 27;
            float s = 0.f;
            #pragma unroll
            for (int zz = 0; zz < 3; ++zz)
                #pragma unroll
                for (int dy = 0; dy < 3; ++dy) {
                    int iy = y + dy - 1;
                    if ((unsigned)iy < 16u) {
                        float v  = xs[ch][zz][iy][xx];
                        float vm = __shfl_up(v, 1, 16);
                        float vp = __shfl_down(v, 1, 16);
                        float w0 = wc[zz * 9 + dy * 3 + 0];
                        float w1 = wc[zz * 9 + dy * 3 + 1];
                        float w2 = wc[zz * 9 + dy * 3 + 2];
                        if (xx > 0)  s += vm * w0;
                        s += v * w1;
                        if (xx < 15) s += vp * w2;
                    }
                }
            float sc = qg[c] * rsqrtf(qv[c] + 1e-5f);
            float sh = qb[c] - qm[c] * sc;
            res[ch] = f2bf(s * sc + sh);
        }
        const int i = z * 256 + tid;
        const int ib = i >> 4;
        short* dstb = qd_t + (long)b * 524288;
        #pragma unroll
        for (int h2 = 0; h2 < 2; ++h2) {
            short8 ov;
            #pragma unroll
            for (int k = 0; k < 8; ++k) ov[k] = res[h2 * 8 + k];
            *(short8*)(dstb + (ib * 4 + (cg >> 1)) * 512 + (((cg * 2 + h2) & 3) * 16 + xx) * 8) = ov;
        }
    } else {  // ---- depthwise kv, stride 2, oz = by - 16 ----
        const int oz = by - 16;
        #pragma unroll 4
        for (int ch = 0; ch < 16; ++ch)
            for (int zz = 0; zz < 3; ++zz) {
                int iz = 2 * oz + zz - 1;
                float val = 0.f;
                if ((unsigned)iz < 16u)
                    val = x[(((b * 128 + c0 + ch) * 16 + iz) * 16 + y) * 16 + xx];
                xs[ch][zz][y][xx] = val;
            }
        __syncthreads();
        const int pos = tid & 63, cq = tid >> 6;
        const int oy = pos >> 3, ox = pos & 7;
        short4v outv;
        #pragma unroll
        for (int cc = 0; cc < 4; ++cc) {
            const int chl = cq * 4 + cc;
            const int c = c0 + chl;
            const float* wc = wkv_dw + c * 27;
            float s = 0.f;
            #pragma unroll
            for (int zz = 0; zz < 3; ++zz)
                #pragma unroll
                for (int dy = 0; dy < 3; ++dy) {
                    int iy = 2 * oy + dy - 1;
                    if ((unsigned)iy < 16u) {
                        #pragma unroll
                        for (int dx = 0; dx < 3; ++dx) {
                            int ix = 2 * ox + dx - 1;
                            if ((unsigned)ix < 16u)
                                s += xs[chl][zz][iy][ix] * wc[zz * 9 + dy * 3 + dx];
                        }
                    }
                }
            float sc = kg[c] * rsqrtf(kv[c] + 1e-5f);
            float sh = kb[c] - km[c] * sc;
            outv[cc] = f2bf(s * sc + sh);
        }
        const int j = oz * 64 + pos;
        const int jb = j >> 4;
        short* dstb = kvd_t + (long)b * 65536;
        *(short4v*)(dstb + (jb * 4 + (cg >> 1)) * 512 +
                    (((cg * 2 + (cq >> 1)) & 3) * 16 + (j & 15)) * 8 + (cq & 1) * 4) = outv;
    }
}

// ---------------- K2: pointwise kv GEMM -> K (pi-frag) + V (PV-frag) ----------------
__global__ __launch_bounds__(256) void pwkv_kernel(
    const short* __restrict__ wkv_bf, const short* __restrict__ kvd_t,
    short* __restrict__ k_t, short* __restrict__ v_t) {
    const int e = blockIdx.x, b = blockIdx.y;
    const int bj = e >> 3, bo = e & 7;
    const int tid = threadIdx.x, lane = tid & 63, wv = tid >> 6;
    const int jl = lane & 15, gq = lane >> 4;
    const int wm = wv >> 1, wn = wv & 1;
    short8 A[4][4];
    #pragma unroll
    for (int m = 0; m < 4; ++m)
        #pragma unroll
        for (int ks = 0; ks < 4; ++ks)
            A[m][ks] = *(const short8*)(wkv_bf + (((bo * 8 + wm * 4 + m) * 4 + ks) * 512) + lane * 8);
    f32x4 acc[4][4];
    #pragma unroll
    for (int m = 0; m < 4; ++m)
        #pragma unroll
        for (int n = 0; n < 4; ++n) acc[m][n] = (f32x4){0.f, 0.f, 0.f, 0.f};
    const short* Bb = kvd_t + (long)b * 65536;
    #pragma unroll
    for (int ks = 0; ks < 4; ++ks)
        #pragma unroll
        for (int n = 0; n < 4; ++n) {
            short8 Bf = *(const short8*)(Bb + (((bj * 8 + wn * 4 + n) * 4 + ks) * 512) + lane * 8);
            #pragma unroll
            for (int m = 0; m < 4; ++m) acc[m][n] = MFMA16(A[m][ks], Bf, acc[m][n]);
        }
    const int hh = bo * 2 + wm;
    if (hh < 8) {
        // K in pi order: frag = jt*2 + (m>>1); pos = lane*8 + (m&1)*4 + r
        short* kf = k_t + ((long)(b * 8 + hh)) * 32768;
        #pragma unroll
        for (int m = 0; m < 4; ++m)
            #pragma unroll
            for (int n = 0; n < 4; ++n) {
                int jt = bj * 8 + wn * 4 + n;
                short4v pk;
                #pragma unroll
                for (int r = 0; r < 4; ++r) pk[r] = f2bf(acc[m][n][r]);
                *(short4v*)(kf + (jt * 2 + (m >> 1)) * 512 + lane * 8 + (m & 1) * 4) = pk;
            }
    } else {
        short* vf = v_t + ((long)(b * 8 + hh - 8)) * 32768;
        #pragma unroll
        for (int m = 0; m < 4; ++m)
            #pragma unroll
            for (int n = 0; n < 4; ++n) {
                int frag = ((bj * 4 + wn * 2 + (n >> 1)) * 4 + m);
                #pragma unroll
                for (int r = 0; r < 4; ++r)
                    vf[frag * 512 + ((jl >> 2) * 16 + gq * 4 + r) * 8 + (n & 1) * 4 + (jl & 3)]
                        = f2bf(acc[m][n][r]);
            }
    }
}

// ---------------- K3: FUSED Q-proj + attention + out-proj + bias, v2 ----------------
// One BLOCK = one 16-row i-tile; 4 waves x 2 heads each (h = wv, wv+4).
// Out-projection accumulated per-wave in registers, combined via one LDS
// reduction + single barrier. Grid 256x4 = 1024 blocks (4096 waves).
__global__ __launch_bounds__(256) void fused_kernel(
    const short* __restrict__ wq_bf, const short* __restrict__ qd_t,
    const short* __restrict__ k_t, const short* __restrict__ v_t,
    const short* __restrict__ wo_bf, const float* __restrict__ bias,
    float* __restrict__ out) {
    __shared__ f32x4 lred[4][8][64];  // 32 KB
    const int it = blockIdx.x, b = blockIdx.y;
    const int tid = threadIdx.x, lane = tid & 63, wv = tid >> 6;
    const int jl = lane & 15, gq = lane >> 4;

    // qd B-fragments (K=128 -> 4 chunks), shared by both heads of this wave
    short8 qdB[4];
    {
        const short* qdb = qd_t + (long)b * 524288;
        #pragma unroll
        for (int kc = 0; kc < 4; ++kc)
            qdB[kc] = *(const short8*)(qdb + (it * 4 + kc) * 512 + lane * 8);
    }

    f32x4 outacc[8];
    #pragma unroll
    for (int o = 0; o < 8; ++o) outacc[o] = (f32x4){0.f, 0.f, 0.f, 0.f};

    #pragma unroll 1
    for (int hi = 0; hi < 2; ++hi) {
        const int h = wv + hi * 4;
        const short* kf = k_t + ((long)(b * 8 + h)) * 32768;
        const short* vf = v_t + ((long)(b * 8 + h)) * 32768;
        // ---- Q-proj: qa[ot] holds Q[h*64 + ot*16 + gq*4 + r][i=jl]
        f32x4 qa[4];
        #pragma unroll
        for (int ot = 0; ot < 4; ++ot) qa[ot] = (f32x4){0.f, 0.f, 0.f, 0.f};
        #pragma unroll
        for (int kc = 0; kc < 4; ++kc)
            #pragma unroll
            for (int ot = 0; ot < 4; ++ot) {
                short8 Af = *(const short8*)(wq_bf + (((h * 4 + ot) * 4 + kc) * 512) + lane * 8);
                qa[ot] = MFMA16(Af, qdB[kc], qa[ot]);
            }
        short8 QB[2];
        QB[0] = pack8(qa[0], qa[1], C2SCALE);
        QB[1] = pack8(qa[2], qa[3], C2SCALE);

        f32x4 O[4];
        #pragma unroll
        for (int m = 0; m < 4; ++m) O[m] = (f32x4){0.f, 0.f, 0.f, 0.f};
        float l = 0.f;

        #pragma unroll 2
        for (int c = 0; c < 8; ++c) {
            f32x4 S[4];
            #pragma unroll
            for (int n = 0; n < 4; ++n) S[n] = (f32x4){0.f, 0.f, 0.f, 0.f};
            #pragma unroll
            for (int n = 0; n < 4; ++n)
                #pragma unroll
                for (int ks = 0; ks < 2; ++ks) {
                    short8 Kf = *(const short8*)(kf + ((c * 4 + n) * 2 + ks) * 512 + lane * 8);
                    S[n] = MFMA16(Kf, QB[ks], S[n]);
                }
            short8 VA[2][4];
            #pragma unroll
            for (int ks2 = 0; ks2 < 2; ++ks2)
                #pragma unroll
                for (int m = 0; m < 4; ++m)
                    VA[ks2][m] = *(const short8*)(vf + ((c * 2 + ks2) * 4 + m) * 512 + lane * 8);
            // max-free softmax
            f32x4 p[4];
            #pragma unroll
            for (int n = 0; n < 4; ++n)
                #pragma unroll
                for (int r = 0; r < 4; ++r) {
                    p[n][r] = exp2f(S[n][r]);
                    l += p[n][r];
                }
            short8 PW[2];
            PW[0] = pack8(p[0], p[1], 1.f);
            PW[1] = pack8(p[2], p[3], 1.f);
            #pragma unroll
            for (int ks2 = 0; ks2 < 2; ++ks2)
                #pragma unroll
                for (int m = 0; m < 4; ++m)
                    O[m] = MFMA16(VA[ks2][m], PW[ks2], O[m]);
        }
        l += __shfl_xor(l, 16, 64);
        l += __shfl_xor(l, 32, 64);
        float inv = 1.f / l;
        short8 PB[2];
        PB[0] = pack8(O[0], O[1], inv);
        PB[1] = pack8(O[2], O[3], inv);
        // out-GEMM for this head
        #pragma unroll
        for (int ks3 = 0; ks3 < 2; ++ks3)
            #pragma unroll
            for (int ot2 = 0; ot2 < 8; ++ot2) {
                short8 Wf = *(const short8*)(wo_bf + (((h * 2 + ks3) * 8 + ot2) * 512) + lane * 8);
                outacc[ot2] = MFMA16(Wf, PB[ks3], outacc[ot2]);
            }
    }
    // ---- cross-wave reduction of out-projection partials ----
    #pragma unroll
    for (int ot2 = 0; ot2 < 8; ++ot2) lred[wv][ot2][lane] = outacc[ot2];
    __syncthreads();
    const int ii = it * 16 + jl;
    #pragma unroll
    for (int k2 = 0; k2 < 2; ++k2) {
        int ot2 = wv * 2 + k2;
        f32x4 s0 = lred[0][ot2][lane];
        f32x4 s1 = lred[1][ot2][lane];
        f32x4 s2 = lred[2][ot2][lane];
        f32x4 s3 = lred[3][ot2][lane];
        #pragma unroll
        for (int r = 0; r < 4; ++r) {
            int co = ot2 * 16 + gq * 4 + r;
            out[((long)(b * 128 + co)) * 4096 + ii] = s0[r] + s1[r] + s2[r] + s3[r] + bias[co];
        }
    }
}

extern "C" void kernel_launch(void* const* d_in, const int* in_sizes, int n_in,
                              void* d_out, int out_size, void* d_ws, size_t ws_size,
                              hipStream_t stream) {
    const float* x      = (const float*)d_in[0];
    const float* wq_dw  = (const float*)d_in[1];
    const float* bnq_g  = (const float*)d_in[2];
    const float* bnq_b  = (const float*)d_in[3];
    const float* bnq_m  = (const float*)d_in[4];
    const float* bnq_v  = (const float*)d_in[5];
    const float* wq_pw  = (const float*)d_in[6];
    const float* wkv_dw = (const float*)d_in[7];
    const float* bnk_g  = (const float*)d_in[8];
    const float* bnk_b  = (const float*)d_in[9];
    const float* bnk_m  = (const float*)d_in[10];
    const float* bnk_v  = (const float*)d_in[11];
    const float* wkv_pw = (const float*)d_in[12];
    const float* w_out  = (const float*)d_in[13];
    const float* b_out  = (const float*)d_in[14];
    float* out = (float*)d_out;

    char* ws = (char*)d_ws;
    short* wq_bf  = (short*)(ws + 0);          //  512*128*2
    short* wkv_bf = (short*)(ws + 131072);     // 1024*128*2
    short* wo_bf  = (short*)(ws + 393216);     //  128*512*2
    short* qd_t   = (short*)(ws + 524288);     // 4*4096*128*2
    short* kvd_t  = (short*)(ws + 4718592);    // 4*512*128*2
    short* k_t    = (short*)(ws + 5242880);    // 4*8*512*64*2
    short* v_t    = (short*)(ws + 7340032);    // 4*8*64*512*2

    dw_kernel<<<dim3(8, 25, 4), dim3(256), 0, stream>>>(
        x, wq_dw, bnq_g, bnq_b, bnq_m, bnq_v,
        wkv_dw, bnk_g, bnk_b, bnk_m, bnk_v,
        wq_pw, wkv_pw, w_out,
        qd_t, kvd_t, wq_bf, wkv_bf, wo_bf);
    pwkv_kernel<<<dim3(32, 4), dim3(256), 0, stream>>>(wkv_bf, kvd_t, k_t, v_t);
    fused_kernel<<<dim3(256, 4), dim3(256), 0, stream>>>(wq_bf, qd_t, k_t, v_t, wo_bf, b_out, out);
}

// Round 9
// 170.894 us; speedup vs baseline: 1.3415x; 1.0876x over previous
//
#include <hip/hip_runtime.h>
#include <hip/hip_bf16.h>

typedef __attribute__((ext_vector_type(8))) short short8;
typedef __attribute__((ext_vector_type(4))) short short4v;
typedef __attribute__((ext_vector_type(4))) float f32x4;

#define MFMA16(a, b, c) __builtin_amdgcn_mfma_f32_16x16x32_bf16((a), (b), (c), 0, 0, 0)

// Plain fragment layout: frag*512 + lane*8 + e (lane = gq*16+jl).
// Pi-permuted k order (accumulator-fed B-operands, lane-local repack):
//   k-slot (ks,gq,e) <-> d = (2*ks + (e>>2))*16 + gq*4 + (e&3)
// A-side partners (K in pwkv, wo in weight conv) pre-stored in pi order.

__device__ __forceinline__ short f2bf(float f) {
    union { __hip_bfloat16 h; short s; } u;
    u.h = __float2bfloat16(f);
    return u.s;
}

__device__ __forceinline__ unsigned pk2(float lo, float hi) {
    unsigned a = (unsigned short)f2bf(lo);
    unsigned b = (unsigned short)f2bf(hi);
    return a | (b << 16);
}

__device__ __forceinline__ short8 pack8(const f32x4 a, const f32x4 b, float s) {
    union { short8 v; unsigned w[4]; } u;
    u.w[0] = pk2(a[0] * s, a[1] * s);
    u.w[1] = pk2(a[2] * s, a[3] * s);
    u.w[2] = pk2(b[0] * s, b[1] * s);
    u.w[3] = pk2(b[2] * s, b[3] * s);
    return u.v;
}

#define C2SCALE 0.18033688011112042f  // (1/8) * log2(e), folded into Q

// ---------------- K1: depthwise q (by 0-15) + depthwise kv (by 16-23)
// ---------------- + weight reorder (by==24); 8 channels/block ----------------
__global__ __launch_bounds__(256) void dw_kernel(
    const float* __restrict__ x,
    const float* __restrict__ wq_dw, const float* __restrict__ qg, const float* __restrict__ qb,
    const float* __restrict__ qm, const float* __restrict__ qv,
    const float* __restrict__ wkv_dw, const float* __restrict__ kg, const float* __restrict__ kb,
    const float* __restrict__ km, const float* __restrict__ kv,
    const float* __restrict__ wq_pw, const float* __restrict__ wkv_pw, const float* __restrict__ wo,
    short* __restrict__ qd_t, short* __restrict__ kvd_t,
    short* __restrict__ wq_bf, short* __restrict__ wkv_bf, short* __restrict__ wo_bf) {
    __shared__ float xs[8][3][16][17];  // ~26 KB
    const int cg = blockIdx.x, by = blockIdx.y, b = blockIdx.z;
    const int tid = threadIdx.x;

    if (by == 24) {  // ---- weight conversion (64 blocks x 256 thr) ----
        const int base = (b * 16 + cg) * 256 + tid;
        for (int i = base; i < 65536; i += 16384) {
            int o = i >> 7, cin = i & 127;
            wq_bf[((o >> 4) * 4 + (cin >> 5)) * 512 + (((cin >> 3) & 3) * 16 + (o & 15)) * 8 + (cin & 7)] = f2bf(wq_pw[i]);
        }
        for (int i = base; i < 131072; i += 16384) {
            int o = i >> 7, cin = i & 127;
            wkv_bf[((o >> 4) * 4 + (cin >> 5)) * 512 + (((cin >> 3) & 3) * 16 + (o & 15)) * 8 + (cin & 7)] = f2bf(wkv_pw[i]);
        }
        // wo in pi-permuted per-head fragment order for the fused out-GEMM
        for (int i = base; i < 65536; i += 16384) {
            int co = i >> 9, cin = i & 511;
            int h = cin >> 6, d2 = cin & 63;
            int m2 = d2 >> 4, gq2 = (d2 >> 2) & 3, r2 = d2 & 3;
            int frag = ((h * 2 + (m2 >> 1)) * 8 + (co >> 4));
            wo_bf[frag * 512 + (gq2 * 16 + (co & 15)) * 8 + (m2 & 1) * 4 + r2] = f2bf(wo[i]);
        }
        return;
    }

    const int y = tid >> 4, xx = tid & 15;
    const int c0 = cg * 8;

    if (by < 16) {  // ---- depthwise q, stride 1, z = by ----
        const int z = by;
        #pragma unroll 4
        for (int ch = 0; ch < 8; ++ch)
            for (int zz = 0; zz < 3; ++zz) {
                int iz = z + zz - 1;
                float val = 0.f;
                if ((unsigned)iz < 16u)
                    val = x[(((b * 128 + c0 + ch) * 16 + iz) * 16 + y) * 16 + xx];
                xs[ch][zz][y][xx] = val;
            }
        __syncthreads();
        short res[8];
        #pragma unroll
        for (int ch = 0; ch < 8; ++ch) {
            const int c = c0 + ch;
            const float* wc = wq_dw + c * 27;
            float s = 0.f;
            #pragma unroll
            for (int zz = 0; zz < 3; ++zz)
                #pragma unroll
                for (int dy = 0; dy < 3; ++dy) {
                    int iy = y + dy - 1;
                    if ((unsigned)iy < 16u) {
                        float v  = xs[ch][zz][iy][xx];
                        float vm = __shfl_up(v, 1, 16);
                        float vp = __shfl_down(v, 1, 16);
                        float w0 = wc[zz * 9 + dy * 3 + 0];
                        float w1 = wc[zz * 9 + dy * 3 + 1];
                        float w2 = wc[zz * 9 + dy * 3 + 2];
                        if (xx > 0)  s += vm * w0;
                        s += v * w1;
                        if (xx < 15) s += vp * w2;
                    }
                }
            float sc = qg[c] * rsqrtf(qv[c] + 1e-5f);
            float sh = qb[c] - qm[c] * sc;
            res[ch] = f2bf(s * sc + sh);
        }
        const int i = z * 256 + tid;
        const int ib = i >> 4;
        short8 ov;
        #pragma unroll
        for (int k = 0; k < 8; ++k) ov[k] = res[k];
        *(short8*)(qd_t + (long)b * 524288 +
                   (ib * 4 + (cg >> 2)) * 512 + ((cg & 3) * 16 + xx) * 8) = ov;
    } else {  // ---- depthwise kv, stride 2, oz = by - 16 ----
        const int oz = by - 16;
        #pragma unroll 4
        for (int ch = 0; ch < 8; ++ch)
            for (int zz = 0; zz < 3; ++zz) {
                int iz = 2 * oz + zz - 1;
                float val = 0.f;
                if ((unsigned)iz < 16u)
                    val = x[(((b * 128 + c0 + ch) * 16 + iz) * 16 + y) * 16 + xx];
                xs[ch][zz][y][xx] = val;
            }
        __syncthreads();
        const int pos = tid & 63, cq = tid >> 6;
        const int oy = pos >> 3, ox = pos & 7;
        union { unsigned u; short s[2]; } pv;
        #pragma unroll
        for (int cc = 0; cc < 2; ++cc) {
            const int chl = cq * 2 + cc;
            const int c = c0 + chl;
            const float* wc = wkv_dw + c * 27;
            float s = 0.f;
            #pragma unroll
            for (int zz = 0; zz < 3; ++zz)
                #pragma unroll
                for (int dy = 0; dy < 3; ++dy) {
                    int iy = 2 * oy + dy - 1;
                    if ((unsigned)iy < 16u) {
                        #pragma unroll
                        for (int dx = 0; dx < 3; ++dx) {
                            int ix = 2 * ox + dx - 1;
                            if ((unsigned)ix < 16u)
                                s += xs[chl][zz][iy][ix] * wc[zz * 9 + dy * 3 + dx];
                        }
                    }
                }
            float sc = kg[c] * rsqrtf(kv[c] + 1e-5f);
            float sh = kb[c] - km[c] * sc;
            pv.s[cc] = f2bf(s * sc + sh);
        }
        const int j = oz * 64 + pos;
        const int jb = j >> 4;
        *(unsigned*)(kvd_t + (long)b * 65536 +
                     (jb * 4 + (cg >> 2)) * 512 + ((cg & 3) * 16 + (j & 15)) * 8 + cq * 2) = pv.u;
    }
}

// ---------------- K2: pointwise kv GEMM, widened grid (256,4) ----------------
// e: bj16 = e>>3 (j-16-tile 0..31), bo = e&7 (o-128-group). Wave: 2 o-16-tiles.
__global__ __launch_bounds__(256) void pwkv_kernel(
    const short* __restrict__ wkv_bf, const short* __restrict__ kvd_t,
    short* __restrict__ k_t, short* __restrict__ v_t) {
    const int e = blockIdx.x, b = blockIdx.y;
    const int bj16 = e >> 3, bo = e & 7;
    const int tid = threadIdx.x, lane = tid & 63, wv = tid >> 6;
    const int jl = lane & 15, gq = lane >> 4;

    short8 A[2][4];
    #pragma unroll
    for (int m = 0; m < 2; ++m) {
        const int ot = bo * 8 + wv * 2 + m;
        #pragma unroll
        for (int ks = 0; ks < 4; ++ks)
            A[m][ks] = *(const short8*)(wkv_bf + ((ot * 4 + ks) * 512) + lane * 8);
    }
    short8 Bf[4];
    #pragma unroll
    for (int ks = 0; ks < 4; ++ks)
        Bf[ks] = *(const short8*)(kvd_t + (long)b * 65536 + ((bj16 * 4 + ks) * 512) + lane * 8);

    f32x4 acc[2];
    acc[0] = (f32x4){0.f, 0.f, 0.f, 0.f};
    acc[1] = (f32x4){0.f, 0.f, 0.f, 0.f};
    #pragma unroll
    for (int ks = 0; ks < 4; ++ks) {
        acc[0] = MFMA16(A[0][ks], Bf[ks], acc[0]);
        acc[1] = MFMA16(A[1][ks], Bf[ks], acc[1]);
    }

    #pragma unroll
    for (int m = 0; m < 2; ++m) {
        const int ot = bo * 8 + wv * 2 + m;
        if (ot < 32) {  // K half: h = ot>>2, within-head d-tile m2 = ot&3
            const int h = ot >> 2, m2 = ot & 3;
            short* kf = k_t + ((long)(b * 8 + h)) * 32768;
            short4v pk;
            #pragma unroll
            for (int r = 0; r < 4; ++r) pk[r] = f2bf(acc[m][r]);
            *(short4v*)(kf + (bj16 * 2 + (m2 >> 1)) * 512 + lane * 8 + (m2 & 1) * 4) = pk;
        } else {        // V half
            const int ot2 = ot - 32;
            const int h = ot2 >> 2, md = ot2 & 3;
            short* vf = v_t + ((long)(b * 8 + h)) * 32768;
            const int frag = (bj16 >> 1) * 4 + md;
            #pragma unroll
            for (int r = 0; r < 4; ++r)
                vf[frag * 512 + ((jl >> 2) * 16 + gq * 4 + r) * 8 + (bj16 & 1) * 4 + (jl & 3)]
                    = f2bf(acc[m][r]);
        }
    }
}

// ---------------- K3: FUSED Q-proj + attention + out-proj + bias (unchanged) ----------------
__global__ __launch_bounds__(256) void fused_kernel(
    const short* __restrict__ wq_bf, const short* __restrict__ qd_t,
    const short* __restrict__ k_t, const short* __restrict__ v_t,
    const short* __restrict__ wo_bf, const float* __restrict__ bias,
    float* __restrict__ out) {
    __shared__ f32x4 lred[4][8][64];  // 32 KB
    const int it = blockIdx.x, b = blockIdx.y;
    const int tid = threadIdx.x, lane = tid & 63, wv = tid >> 6;
    const int jl = lane & 15, gq = lane >> 4;

    short8 qdB[4];
    {
        const short* qdb = qd_t + (long)b * 524288;
        #pragma unroll
        for (int kc = 0; kc < 4; ++kc)
            qdB[kc] = *(const short8*)(qdb + (it * 4 + kc) * 512 + lane * 8);
    }

    f32x4 outacc[8];
    #pragma unroll
    for (int o = 0; o < 8; ++o) outacc[o] = (f32x4){0.f, 0.f, 0.f, 0.f};

    #pragma unroll 1
    for (int hi = 0; hi < 2; ++hi) {
        const int h = wv + hi * 4;
        const short* kf = k_t + ((long)(b * 8 + h)) * 32768;
        const short* vf = v_t + ((long)(b * 8 + h)) * 32768;
        f32x4 qa[4];
        #pragma unroll
        for (int ot = 0; ot < 4; ++ot) qa[ot] = (f32x4){0.f, 0.f, 0.f, 0.f};
        #pragma unroll
        for (int kc = 0; kc < 4; ++kc)
            #pragma unroll
            for (int ot = 0; ot < 4; ++ot) {
                short8 Af = *(const short8*)(wq_bf + (((h * 4 + ot) * 4 + kc) * 512) + lane * 8);
                qa[ot] = MFMA16(Af, qdB[kc], qa[ot]);
            }
        short8 QB[2];
        QB[0] = pack8(qa[0], qa[1], C2SCALE);
        QB[1] = pack8(qa[2], qa[3], C2SCALE);

        f32x4 O[4];
        #pragma unroll
        for (int m = 0; m < 4; ++m) O[m] = (f32x4){0.f, 0.f, 0.f, 0.f};
        float l = 0.f;

        #pragma unroll 2
        for (int c = 0; c < 8; ++c) {
            f32x4 S[4];
            #pragma unroll
            for (int n = 0; n < 4; ++n) S[n] = (f32x4){0.f, 0.f, 0.f, 0.f};
            #pragma unroll
            for (int n = 0; n < 4; ++n)
                #pragma unroll
                for (int ks = 0; ks < 2; ++ks) {
                    short8 Kf = *(const short8*)(kf + ((c * 4 + n) * 2 + ks) * 512 + lane * 8);
                    S[n] = MFMA16(Kf, QB[ks], S[n]);
                }
            short8 VA[2][4];
            #pragma unroll
            for (int ks2 = 0; ks2 < 2; ++ks2)
                #pragma unroll
                for (int m = 0; m < 4; ++m)
                    VA[ks2][m] = *(const short8*)(vf + ((c * 2 + ks2) * 4 + m) * 512 + lane * 8);
            f32x4 p[4];
            #pragma unroll
            for (int n = 0; n < 4; ++n)
                #pragma unroll
                for (int r = 0; r < 4; ++r) {
                    p[n][r] = exp2f(S[n][r]);
                    l += p[n][r];
                }
            short8 PW[2];
            PW[0] = pack8(p[0], p[1], 1.f);
            PW[1] = pack8(p[2], p[3], 1.f);
            #pragma unroll
            for (int ks2 = 0; ks2 < 2; ++ks2)
                #pragma unroll
                for (int m = 0; m < 4; ++m)
                    O[m] = MFMA16(VA[ks2][m], PW[ks2], O[m]);
        }
        l += __shfl_xor(l, 16, 64);
        l += __shfl_xor(l, 32, 64);
        float inv = 1.f / l;
        short8 PB[2];
        PB[0] = pack8(O[0], O[1], inv);
        PB[1] = pack8(O[2], O[3], inv);
        #pragma unroll
        for (int ks3 = 0; ks3 < 2; ++ks3)
            #pragma unroll
            for (int ot2 = 0; ot2 < 8; ++ot2) {
                short8 Wf = *(const short8*)(wo_bf + (((h * 2 + ks3) * 8 + ot2) * 512) + lane * 8);
                outacc[ot2] = MFMA16(Wf, PB[ks3], outacc[ot2]);
            }
    }
    #pragma unroll
    for (int ot2 = 0; ot2 < 8; ++ot2) lred[wv][ot2][lane] = outacc[ot2];
    __syncthreads();
    const int ii = it * 16 + jl;
    #pragma unroll
    for (int k2 = 0; k2 < 2; ++k2) {
        int ot2 = wv * 2 + k2;
        f32x4 s0 = lred[0][ot2][lane];
        f32x4 s1 = lred[1][ot2][lane];
        f32x4 s2 = lred[2][ot2][lane];
        f32x4 s3 = lred[3][ot2][lane];
        #pragma unroll
        for (int r = 0; r < 4; ++r) {
            int co = ot2 * 16 + gq * 4 + r;
            out[((long)(b * 128 + co)) * 4096 + ii] = s0[r] + s1[r] + s2[r] + s3[r] + bias[co];
        }
    }
}

extern "C" void kernel_launch(void* const* d_in, const int* in_sizes, int n_in,
                              void* d_out, int out_size, void* d_ws, size_t ws_size,
                              hipStream_t stream) {
    const float* x      = (const float*)d_in[0];
    const float* wq_dw  = (const float*)d_in[1];
    const float* bnq_g  = (const float*)d_in[2];
    const float* bnq_b  = (const float*)d_in[3];
    const float* bnq_m  = (const float*)d_in[4];
    const float* bnq_v  = (const float*)d_in[5];
    const float* wq_pw  = (const float*)d_in[6];
    const float* wkv_dw = (const float*)d_in[7];
    const float* bnk_g  = (const float*)d_in[8];
    const float* bnk_b  = (const float*)d_in[9];
    const float* bnk_m  = (const float*)d_in[10];
    const float* bnk_v  = (const float*)d_in[11];
    const float* wkv_pw = (const float*)d_in[12];
    const float* w_out  = (const float*)d_in[13];
    const float* b_out  = (const float*)d_in[14];
    float* out = (float*)d_out;

    char* ws = (char*)d_ws;
    short* wq_bf  = (short*)(ws + 0);          //  512*128*2
    short* wkv_bf = (short*)(ws + 131072);     // 1024*128*2
    short* wo_bf  = (short*)(ws + 393216);     //  128*512*2
    short* qd_t   = (short*)(ws + 524288);     // 4*4096*128*2
    short* kvd_t  = (short*)(ws + 4718592);    // 4*512*128*2
    short* k_t    = (short*)(ws + 5242880);    // 4*8*512*64*2
    short* v_t    = (short*)(ws + 7340032);    // 4*8*64*512*2

    dw_kernel<<<dim3(16, 25, 4), dim3(256), 0, stream>>>(
        x, wq_dw, bnq_g, bnq_b, bnq_m, bnq_v,
        wkv_dw, bnk_g, bnk_b, bnk_m, bnk_v,
        wq_pw, wkv_pw, w_out,
        qd_t, kvd_t, wq_bf, wkv_bf, wo_bf);
    pwkv_kernel<<<dim3(256, 4), dim3(256), 0, stream>>>(wkv_bf, kvd_t, k_t, v_t);
    fused_kernel<<<dim3(256, 4), dim3(256), 0, stream>>>(wq_bf, qd_t, k_t, v_t, wo_bf, b_out, out);
}

// Round 10
// 162.205 us; speedup vs baseline: 1.4134x; 1.0536x over previous
//
#include <hip/hip_runtime.h>
#include <hip/hip_bf16.h>

typedef __attribute__((ext_vector_type(8))) short short8;
typedef __attribute__((ext_vector_type(4))) short short4v;
typedef __attribute__((ext_vector_type(4))) float f32x4;

#define MFMA16(a, b, c) __builtin_amdgcn_mfma_f32_16x16x32_bf16((a), (b), (c), 0, 0, 0)

// Plain fragment layout: frag*512 + lane*8 + e (lane = gq*16+jl).
// Pi-permuted k order (accumulator-fed B-operands, lane-local repack):
//   k-slot (ks,gq,e) <-> d = (2*ks + (e>>2))*16 + gq*4 + (e&3)
// A-side partners (K in pwkv, wo in weight conv) pre-stored in pi order.

__device__ __forceinline__ short f2bf(float f) {
    union { __hip_bfloat16 h; short s; } u;
    u.h = __float2bfloat16(f);
    return u.s;
}

__device__ __forceinline__ unsigned pk2(float lo, float hi) {
    unsigned a = (unsigned short)f2bf(lo);
    unsigned b = (unsigned short)f2bf(hi);
    return a | (b << 16);
}

__device__ __forceinline__ short8 pack8(const f32x4 a, const f32x4 b, float s) {
    union { short8 v; unsigned w[4]; } u;
    u.w[0] = pk2(a[0] * s, a[1] * s);
    u.w[1] = pk2(a[2] * s, a[3] * s);
    u.w[2] = pk2(b[0] * s, b[1] * s);
    u.w[3] = pk2(b[2] * s, b[3] * s);
    return u.v;
}

#define C2SCALE 0.18033688011112042f  // (1/8) * log2(e), folded into Q

// ---------------- K1: depthwise q (by 0-15) + depthwise kv (by 16-23)
// ---------------- + weight reorder (by==24); 8 channels/block ----------------
__global__ __launch_bounds__(256) void dw_kernel(
    const float* __restrict__ x,
    const float* __restrict__ wq_dw, const float* __restrict__ qg, const float* __restrict__ qb,
    const float* __restrict__ qm, const float* __restrict__ qv,
    const float* __restrict__ wkv_dw, const float* __restrict__ kg, const float* __restrict__ kb,
    const float* __restrict__ km, const float* __restrict__ kv,
    const float* __restrict__ wq_pw, const float* __restrict__ wkv_pw, const float* __restrict__ wo,
    short* __restrict__ qd_t, short* __restrict__ kvd_t,
    short* __restrict__ wq_bf, short* __restrict__ wkv_bf, short* __restrict__ wo_bf) {
    __shared__ float xs[8][3][16][17];  // ~26 KB
    const int cg = blockIdx.x, by = blockIdx.y, b = blockIdx.z;
    const int tid = threadIdx.x;

    if (by == 24) {  // ---- weight conversion (64 blocks x 256 thr) ----
        const int base = (b * 16 + cg) * 256 + tid;
        for (int i = base; i < 65536; i += 16384) {
            int o = i >> 7, cin = i & 127;
            wq_bf[((o >> 4) * 4 + (cin >> 5)) * 512 + (((cin >> 3) & 3) * 16 + (o & 15)) * 8 + (cin & 7)] = f2bf(wq_pw[i]);
        }
        for (int i = base; i < 131072; i += 16384) {
            int o = i >> 7, cin = i & 127;
            wkv_bf[((o >> 4) * 4 + (cin >> 5)) * 512 + (((cin >> 3) & 3) * 16 + (o & 15)) * 8 + (cin & 7)] = f2bf(wkv_pw[i]);
        }
        // wo in pi-permuted per-head fragment order for the fused out-GEMM
        for (int i = base; i < 65536; i += 16384) {
            int co = i >> 9, cin = i & 511;
            int h = cin >> 6, d2 = cin & 63;
            int m2 = d2 >> 4, gq2 = (d2 >> 2) & 3, r2 = d2 & 3;
            int frag = ((h * 2 + (m2 >> 1)) * 8 + (co >> 4));
            wo_bf[frag * 512 + (gq2 * 16 + (co & 15)) * 8 + (m2 & 1) * 4 + r2] = f2bf(wo[i]);
        }
        return;
    }

    const int y = tid >> 4, xx = tid & 15;
    const int c0 = cg * 8;

    if (by < 16) {  // ---- depthwise q, stride 1, z = by ----
        const int z = by;
        #pragma unroll 4
        for (int ch = 0; ch < 8; ++ch)
            for (int zz = 0; zz < 3; ++zz) {
                int iz = z + zz - 1;
                float val = 0.f;
                if ((unsigned)iz < 16u)
                    val = x[(((b * 128 + c0 + ch) * 16 + iz) * 16 + y) * 16 + xx];
                xs[ch][zz][y][xx] = val;
            }
        __syncthreads();
        short res[8];
        #pragma unroll
        for (int ch = 0; ch < 8; ++ch) {
            const int c = c0 + ch;
            const float* wc = wq_dw + c * 27;
            float s = 0.f;
            #pragma unroll
            for (int zz = 0; zz < 3; ++zz)
                #pragma unroll
                for (int dy = 0; dy < 3; ++dy) {
                    int iy = y + dy - 1;
                    if ((unsigned)iy < 16u) {
                        float v  = xs[ch][zz][iy][xx];
                        float vm = __shfl_up(v, 1, 16);
                        float vp = __shfl_down(v, 1, 16);
                        float w0 = wc[zz * 9 + dy * 3 + 0];
                        float w1 = wc[zz * 9 + dy * 3 + 1];
                        float w2 = wc[zz * 9 + dy * 3 + 2];
                        if (xx > 0)  s += vm * w0;
                        s += v * w1;
                        if (xx < 15) s += vp * w2;
                    }
                }
            float sc = qg[c] * rsqrtf(qv[c] + 1e-5f);
            float sh = qb[c] - qm[c] * sc;
            res[ch] = f2bf(s * sc + sh);
        }
        const int i = z * 256 + tid;
        const int ib = i >> 4;
        short8 ov;
        #pragma unroll
        for (int k = 0; k < 8; ++k) ov[k] = res[k];
        *(short8*)(qd_t + (long)b * 524288 +
                   (ib * 4 + (cg >> 2)) * 512 + ((cg & 3) * 16 + xx) * 8) = ov;
    } else {  // ---- depthwise kv, stride 2, oz = by - 16 ----
        const int oz = by - 16;
        #pragma unroll 4
        for (int ch = 0; ch < 8; ++ch)
            for (int zz = 0; zz < 3; ++zz) {
                int iz = 2 * oz + zz - 1;
                float val = 0.f;
                if ((unsigned)iz < 16u)
                    val = x[(((b * 128 + c0 + ch) * 16 + iz) * 16 + y) * 16 + xx];
                xs[ch][zz][y][xx] = val;
            }
        __syncthreads();
        const int pos = tid & 63, cq = tid >> 6;
        const int oy = pos >> 3, ox = pos & 7;
        union { unsigned u; short s[2]; } pv;
        #pragma unroll
        for (int cc = 0; cc < 2; ++cc) {
            const int chl = cq * 2 + cc;
            const int c = c0 + chl;
            const float* wc = wkv_dw + c * 27;
            float s = 0.f;
            #pragma unroll
            for (int zz = 0; zz < 3; ++zz)
                #pragma unroll
                for (int dy = 0; dy < 3; ++dy) {
                    int iy = 2 * oy + dy - 1;
                    if ((unsigned)iy < 16u) {
                        #pragma unroll
                        for (int dx = 0; dx < 3; ++dx) {
                            int ix = 2 * ox + dx - 1;
                            if ((unsigned)ix < 16u)
                                s += xs[chl][zz][iy][ix] * wc[zz * 9 + dy * 3 + dx];
                        }
                    }
                }
            float sc = kg[c] * rsqrtf(kv[c] + 1e-5f);
            float sh = kb[c] - km[c] * sc;
            pv.s[cc] = f2bf(s * sc + sh);
        }
        const int j = oz * 64 + pos;
        const int jb = j >> 4;
        *(unsigned*)(kvd_t + (long)b * 65536 +
                     (jb * 4 + (cg >> 2)) * 512 + ((cg & 3) * 16 + (j & 15)) * 8 + cq * 2) = pv.u;
    }
}

// ---------------- K2: pointwise kv GEMM, widened grid (256,4) ----------------
__global__ __launch_bounds__(256) void pwkv_kernel(
    const short* __restrict__ wkv_bf, const short* __restrict__ kvd_t,
    short* __restrict__ k_t, short* __restrict__ v_t) {
    const int e = blockIdx.x, b = blockIdx.y;
    const int bj16 = e >> 3, bo = e & 7;
    const int tid = threadIdx.x, lane = tid & 63, wv = tid >> 6;
    const int jl = lane & 15, gq = lane >> 4;

    short8 A[2][4];
    #pragma unroll
    for (int m = 0; m < 2; ++m) {
        const int ot = bo * 8 + wv * 2 + m;
        #pragma unroll
        for (int ks = 0; ks < 4; ++ks)
            A[m][ks] = *(const short8*)(wkv_bf + ((ot * 4 + ks) * 512) + lane * 8);
    }
    short8 Bf[4];
    #pragma unroll
    for (int ks = 0; ks < 4; ++ks)
        Bf[ks] = *(const short8*)(kvd_t + (long)b * 65536 + ((bj16 * 4 + ks) * 512) + lane * 8);

    f32x4 acc[2];
    acc[0] = (f32x4){0.f, 0.f, 0.f, 0.f};
    acc[1] = (f32x4){0.f, 0.f, 0.f, 0.f};
    #pragma unroll
    for (int ks = 0; ks < 4; ++ks) {
        acc[0] = MFMA16(A[0][ks], Bf[ks], acc[0]);
        acc[1] = MFMA16(A[1][ks], Bf[ks], acc[1]);
    }

    #pragma unroll
    for (int m = 0; m < 2; ++m) {
        const int ot = bo * 8 + wv * 2 + m;
        if (ot < 32) {  // K half
            const int h = ot >> 2, m2 = ot & 3;
            short* kf = k_t + ((long)(b * 8 + h)) * 32768;
            short4v pk;
            #pragma unroll
            for (int r = 0; r < 4; ++r) pk[r] = f2bf(acc[m][r]);
            *(short4v*)(kf + (bj16 * 2 + (m2 >> 1)) * 512 + lane * 8 + (m2 & 1) * 4) = pk;
        } else {        // V half
            const int ot2 = ot - 32;
            const int h = ot2 >> 2, md = ot2 & 3;
            short* vf = v_t + ((long)(b * 8 + h)) * 32768;
            const int frag = (bj16 >> 1) * 4 + md;
            #pragma unroll
            for (int r = 0; r < 4; ++r)
                vf[frag * 512 + ((jl >> 2) * 16 + gq * 4 + r) * 8 + (bj16 & 1) * 4 + (jl & 3)]
                    = f2bf(acc[m][r]);
        }
    }
}

// ---------------- K3: FUSED v3 — K reg-double-buffer, setprio, XCD swizzle ----------------
// One block = one 16-row i-tile; 4 waves x 2 heads. K of chunk c+1 prefetched
// into registers while chunk c computes; V issued at chunk start. Grid flat
// 1024, decoded so each XCD serves one batch (bid%8 -> b = (bid&7)>>1).
#define CHUNK_BODY(cc, KCUR, KNEXT, PF)                                              \
    {                                                                                \
        short8 VA[8];                                                                \
        _Pragma("unroll")                                                            \
        for (int f = 0; f < 8; ++f)                                                  \
            VA[f] = *(const short8*)(vf + ((cc) * 8 + f) * 512 + lane * 8);          \
        if (PF) {                                                                    \
            _Pragma("unroll")                                                        \
            for (int f = 0; f < 8; ++f)                                              \
                KNEXT[f] = *(const short8*)(kf + (((cc) + 1) * 8 + f) * 512 + lane * 8); \
        }                                                                            \
        f32x4 S[4];                                                                  \
        _Pragma("unroll")                                                            \
        for (int n = 0; n < 4; ++n) S[n] = (f32x4){0.f, 0.f, 0.f, 0.f};              \
        __builtin_amdgcn_s_setprio(1);                                               \
        _Pragma("unroll")                                                            \
        for (int n = 0; n < 4; ++n) {                                                \
            S[n] = MFMA16(KCUR[n * 2 + 0], QB[0], S[n]);                             \
            S[n] = MFMA16(KCUR[n * 2 + 1], QB[1], S[n]);                             \
        }                                                                            \
        __builtin_amdgcn_s_setprio(0);                                               \
        _Pragma("unroll")                                                            \
        for (int n = 0; n < 4; ++n)                                                  \
            _Pragma("unroll")                                                        \
            for (int r = 0; r < 4; ++r) {                                            \
                S[n][r] = exp2f(S[n][r]);                                            \
                l += S[n][r];                                                        \
            }                                                                        \
        short8 PW[2];                                                                \
        PW[0] = pack8(S[0], S[1], 1.f);                                              \
        PW[1] = pack8(S[2], S[3], 1.f);                                              \
        __builtin_amdgcn_s_setprio(1);                                               \
        _Pragma("unroll")                                                            \
        for (int m = 0; m < 4; ++m) {                                                \
            O[m] = MFMA16(VA[m], PW[0], O[m]);                                       \
            O[m] = MFMA16(VA[4 + m], PW[1], O[m]);                                   \
        }                                                                            \
        __builtin_amdgcn_s_setprio(0);                                               \
    }

__global__ __launch_bounds__(256) void fused_kernel(
    const short* __restrict__ wq_bf, const short* __restrict__ qd_t,
    const short* __restrict__ k_t, const short* __restrict__ v_t,
    const short* __restrict__ wo_bf, const float* __restrict__ bias,
    float* __restrict__ out) {
    __shared__ f32x4 lred[4][8][64];  // 32 KB
    const int bid = blockIdx.x;
    const int b = (bid & 7) >> 1;                    // XCD-resident batch
    const int it = ((bid >> 3) << 1) | (bid & 1);    // i-tile 0..255 (bijective)
    const int tid = threadIdx.x, lane = tid & 63, wv = tid >> 6;
    const int jl = lane & 15, gq = lane >> 4;

    short8 qdB[4];
    {
        const short* qdb = qd_t + (long)b * 524288;
        #pragma unroll
        for (int kc = 0; kc < 4; ++kc)
            qdB[kc] = *(const short8*)(qdb + (it * 4 + kc) * 512 + lane * 8);
    }

    f32x4 outacc[8];
    #pragma unroll
    for (int o = 0; o < 8; ++o) outacc[o] = (f32x4){0.f, 0.f, 0.f, 0.f};

    #pragma unroll 1
    for (int hi = 0; hi < 2; ++hi) {
        const int h = wv + hi * 4;
        const short* kf = k_t + ((long)(b * 8 + h)) * 32768;
        const short* vf = v_t + ((long)(b * 8 + h)) * 32768;
        // ---- Q-proj
        f32x4 qa[4];
        #pragma unroll
        for (int ot = 0; ot < 4; ++ot) qa[ot] = (f32x4){0.f, 0.f, 0.f, 0.f};
        #pragma unroll
        for (int kc = 0; kc < 4; ++kc)
            #pragma unroll
            for (int ot = 0; ot < 4; ++ot) {
                short8 Af = *(const short8*)(wq_bf + (((h * 4 + ot) * 4 + kc) * 512) + lane * 8);
                qa[ot] = MFMA16(Af, qdB[kc], qa[ot]);
            }
        short8 QB[2];
        QB[0] = pack8(qa[0], qa[1], C2SCALE);
        QB[1] = pack8(qa[2], qa[3], C2SCALE);

        f32x4 O[4];
        #pragma unroll
        for (int m = 0; m < 4; ++m) O[m] = (f32x4){0.f, 0.f, 0.f, 0.f};
        float l = 0.f;

        // K double-buffer prologue: chunk 0
        short8 KA[8], KB[8];
        #pragma unroll
        for (int f = 0; f < 8; ++f)
            KA[f] = *(const short8*)(kf + f * 512 + lane * 8);

        #pragma unroll 1
        for (int cp = 0; cp < 4; ++cp) {
            const int c0c = cp * 2;
            CHUNK_BODY(c0c, KA, KB, 1)
            CHUNK_BODY(c0c + 1, KB, KA, (cp < 3))
        }

        l += __shfl_xor(l, 16, 64);
        l += __shfl_xor(l, 32, 64);
        float inv = 1.f / l;
        short8 PB[2];
        PB[0] = pack8(O[0], O[1], inv);
        PB[1] = pack8(O[2], O[3], inv);
        // out-GEMM for this head
        #pragma unroll
        for (int ks3 = 0; ks3 < 2; ++ks3)
            #pragma unroll
            for (int ot2 = 0; ot2 < 8; ++ot2) {
                short8 Wf = *(const short8*)(wo_bf + (((h * 2 + ks3) * 8 + ot2) * 512) + lane * 8);
                outacc[ot2] = MFMA16(Wf, PB[ks3], outacc[ot2]);
            }
    }
    // ---- cross-wave reduction of out-projection partials ----
    #pragma unroll
    for (int ot2 = 0; ot2 < 8; ++ot2) lred[wv][ot2][lane] = outacc[ot2];
    __syncthreads();
    const int ii = it * 16 + jl;
    #pragma unroll
    for (int k2 = 0; k2 < 2; ++k2) {
        int ot2 = wv * 2 + k2;
        f32x4 s0 = lred[0][ot2][lane];
        f32x4 s1 = lred[1][ot2][lane];
        f32x4 s2 = lred[2][ot2][lane];
        f32x4 s3 = lred[3][ot2][lane];
        #pragma unroll
        for (int r = 0; r < 4; ++r) {
            int co = ot2 * 16 + gq * 4 + r;
            out[((long)(b * 128 + co)) * 4096 + ii] = s0[r] + s1[r] + s2[r] + s3[r] + bias[co];
        }
    }
}

extern "C" void kernel_launch(void* const* d_in, const int* in_sizes, int n_in,
                              void* d_out, int out_size, void* d_ws, size_t ws_size,
                              hipStream_t stream) {
    const float* x      = (const float*)d_in[0];
    const float* wq_dw  = (const float*)d_in[1];
    const float* bnq_g  = (const float*)d_in[2];
    const float* bnq_b  = (const float*)d_in[3];
    const float* bnq_m  = (const float*)d_in[4];
    const float* bnq_v  = (const float*)d_in[5];
    const float* wq_pw  = (const float*)d_in[6];
    const float* wkv_dw = (const float*)d_in[7];
    const float* bnk_g  = (const float*)d_in[8];
    const float* bnk_b  = (const float*)d_in[9];
    const float* bnk_m  = (const float*)d_in[10];
    const float* bnk_v  = (const float*)d_in[11];
    const float* wkv_pw = (const float*)d_in[12];
    const float* w_out  = (const float*)d_in[13];
    const float* b_out  = (const float*)d_in[14];
    float* out = (float*)d_out;

    char* ws = (char*)d_ws;
    short* wq_bf  = (short*)(ws + 0);          //  512*128*2
    short* wkv_bf = (short*)(ws + 131072);     // 1024*128*2
    short* wo_bf  = (short*)(ws + 393216);     //  128*512*2
    short* qd_t   = (short*)(ws + 524288);     // 4*4096*128*2
    short* kvd_t  = (short*)(ws + 4718592);    // 4*512*128*2
    short* k_t    = (short*)(ws + 5242880);    // 4*8*512*64*2
    short* v_t    = (short*)(ws + 7340032);    // 4*8*64*512*2

    dw_kernel<<<dim3(16, 25, 4), dim3(256), 0, stream>>>(
        x, wq_dw, bnq_g, bnq_b, bnq_m, bnq_v,
        wkv_dw, bnk_g, bnk_b, bnk_m, bnk_v,
        wq_pw, wkv_pw, w_out,
        qd_t, kvd_t, wq_bf, wkv_bf, wo_bf);
    pwkv_kernel<<<dim3(256, 4), dim3(256), 0, stream>>>(wkv_bf, kvd_t, k_t, v_t);
    fused_kernel<<<dim3(1024), dim3(256), 0, stream>>>(wq_bf, qd_t, k_t, v_t, wo_bf, b_out, out);
}